// Round 1
// baseline (730.356 us; speedup 1.0000x reference)
//
#include <hip/hip_runtime.h>
#include <hip/hip_bf16.h>
#include <stdint.h>

#define IN_F 4096
#define OUT_F 4096
#define MTOK 8192
#define TOPX_N 10

typedef __bf16 bf16x8 __attribute__((ext_vector_type(8)));
typedef float f32x4 __attribute__((ext_vector_type(4)));

__device__ __forceinline__ void gld_lds16(const void* g, void* l) {
    __builtin_amdgcn_global_load_lds((const __attribute__((address_space(1))) void*)g,
                                     (__attribute__((address_space(3))) void*)l, 16, 0, 0);
}

// ---------------------------------------------------------------------------
// 1) Dequant: W^T[j][k] = lut[j][code(k,j)], bf16, layout (OUT_F, IN_F)
//    thread t -> (word w = t>>12, col j = t&4095); writes 8 contiguous k.
// ---------------------------------------------------------------------------
__global__ void k_dequant(const int* __restrict__ qw, const float* __restrict__ lut,
                          __bf16* __restrict__ Wt) {
    int t = blockIdx.x * 256 + threadIdx.x;
    int j = t & (OUT_F - 1);
    int w = t >> 12;
    unsigned q = ((const unsigned*)qw)[(size_t)w * OUT_F + j];
    const float* lp = lut + (size_t)j * 16;
    bf16x8 v;
#pragma unroll
    for (int i = 0; i < 8; ++i) {
        v[i] = (__bf16)lp[(q >> (4 * i)) & 15];
    }
    *(bf16x8*)(Wt + (size_t)j * IN_F + w * 8) = v;
}

// ---------------------------------------------------------------------------
// 2) CSR outliers: row r owns interval [rows[r], rows[r+1]); no atomics needed.
// ---------------------------------------------------------------------------
__global__ void k_csr(const int* __restrict__ rows, const int* __restrict__ cols,
                      const float* __restrict__ vals, __bf16* __restrict__ Wt) {
    int r = blockIdx.x * 256 + threadIdx.x;
    if (r >= OUT_F) return;
    int s = rows[r], e = rows[r + 1];
    __bf16* wrp = Wt + (size_t)r * IN_F;
    for (int n = s; n < e; ++n) {
        int c = cols[n];
        wrp[c] = (__bf16)((float)wrp[c] + vals[n]);
    }
}

// ---------------------------------------------------------------------------
// 3) topX dense outlier columns: W^T[fri[t]][i] += full_rows[i][t]
// ---------------------------------------------------------------------------
__global__ void k_topx(const float* __restrict__ fr, const int* __restrict__ fri,
                       __bf16* __restrict__ Wt) {
    int i = blockIdx.x * 256 + threadIdx.x;
    if (i >= IN_F) return;
#pragma unroll
    for (int t = 0; t < TOPX_N; ++t) {
        int j = fri[t];
        __bf16* p = Wt + (size_t)j * IN_F + i;
        *p = (__bf16)((float)*p + fr[(size_t)i * TOPX_N + t]);
    }
}

// ---------------------------------------------------------------------------
// 4) x fp32 -> bf16 (8 elements/thread)
// ---------------------------------------------------------------------------
__global__ void k_cvt(const float* __restrict__ x, __bf16* __restrict__ xb) {
    size_t t = (size_t)blockIdx.x * 256 + threadIdx.x;
    const float4* p = (const float4*)x + 2 * t;
    float4 a = p[0], b = p[1];
    bf16x8 v;
    v[0] = (__bf16)a.x; v[1] = (__bf16)a.y; v[2] = (__bf16)a.z; v[3] = (__bf16)a.w;
    v[4] = (__bf16)b.x; v[5] = (__bf16)b.y; v[6] = (__bf16)b.z; v[7] = (__bf16)b.w;
    ((bf16x8*)xb)[t] = v;
}

// ---------------------------------------------------------------------------
// 5) GEMM: C(8192x4096) = A(8192x4096,bf16) * B^T(4096x4096,bf16) + bias
//    m97 structure: 128x128 tile, BK=32, 4 waves x (4x4) 16x16x32 MFMAs,
//    global_load_lds width=16 staging, 2-barrier K-loop.
// ---------------------------------------------------------------------------
__global__ __launch_bounds__(256) void k_gemm(const __bf16* __restrict__ A,
                                              const __bf16* __restrict__ Bt,
                                              const float* __restrict__ bias,
                                              float* __restrict__ C) {
    __shared__ __align__(16) __bf16 As[128 * 32];
    __shared__ __align__(16) __bf16 Bs[128 * 32];
    const int tid = threadIdx.x;
    const int wave = tid >> 6;
    const int lane = tid & 63;
    const int m0 = blockIdx.y * 128;
    const int n0 = blockIdx.x * 128;
    const int wr = (wave >> 1) * 64;   // wave row offset within 128 tile
    const int wc = (wave & 1) * 64;    // wave col offset
    const int lrow = lane & 15;
    const int lk = lane >> 4;          // quad 0..3

    // staging: LDS byte o -> tile row o>>6, k-byte o&63 (rows are 64B = 32 bf16)
    const int o0 = wave * 2048 + lane * 16;
    const int o1 = o0 + 1024;
    const int r0 = o0 >> 6, kb0 = o0 & 63;
    const int r1 = o1 >> 6, kb1 = o1 & 63;

    const char* gA0 = (const char*)(A + (size_t)(m0 + r0) * IN_F) + kb0;
    const char* gA1 = (const char*)(A + (size_t)(m0 + r1) * IN_F) + kb1;
    const char* gB0 = (const char*)(Bt + (size_t)(n0 + r0) * IN_F) + kb0;
    const char* gB1 = (const char*)(Bt + (size_t)(n0 + r1) * IN_F) + kb1;
    char* lA0 = (char*)As + o0;
    char* lA1 = (char*)As + o1;
    char* lB0 = (char*)Bs + o0;
    char* lB1 = (char*)Bs + o1;

    f32x4 acc[4][4] = {};

    for (int k0 = 0; k0 < IN_F; k0 += 32) {
        gld_lds16(gA0, lA0);
        gld_lds16(gA1, lA1);
        gld_lds16(gB0, lB0);
        gld_lds16(gB1, lB1);
        gA0 += 64; gA1 += 64; gB0 += 64; gB1 += 64;
        __syncthreads();   // compiler drains vmcnt(0) before s_barrier

        bf16x8 af[4], bf[4];
#pragma unroll
        for (int i = 0; i < 4; ++i)
            af[i] = *(const bf16x8*)(As + (wr + i * 16 + lrow) * 32 + lk * 8);
#pragma unroll
        for (int j = 0; j < 4; ++j)
            bf[j] = *(const bf16x8*)(Bs + (wc + j * 16 + lrow) * 32 + lk * 8);

#pragma unroll
        for (int i = 0; i < 4; ++i)
#pragma unroll
            for (int j = 0; j < 4; ++j)
                acc[i][j] = __builtin_amdgcn_mfma_f32_16x16x32_bf16(af[i], bf[j], acc[i][j], 0, 0, 0);

        __syncthreads();   // protect LDS before next stage overwrites
    }

    // epilogue: C/D layout col=lane&15, row=(lane>>4)*4+reg  (m89/m91-verified)
#pragma unroll
    for (int j = 0; j < 4; ++j) {
        const int col = n0 + wc + j * 16 + lrow;
        const float bj = bias[col];
#pragma unroll
        for (int i = 0; i < 4; ++i) {
            const int mrow = m0 + wr + i * 16 + lk * 4;
#pragma unroll
            for (int r = 0; r < 4; ++r) {
                C[(size_t)(mrow + r) * OUT_F + col] = acc[i][j][r] + bj;
            }
        }
    }
}

extern "C" void kernel_launch(void* const* d_in, const int* in_sizes, int n_in,
                              void* d_out, int out_size, void* d_ws, size_t ws_size,
                              hipStream_t stream) {
    const float* x         = (const float*)d_in[0];
    const int*   qweight   = (const int*)d_in[1];
    const float* lut       = (const float*)d_in[2];
    const float* bias      = (const float*)d_in[3];
    const int*   rows      = (const int*)d_in[4];
    const int*   cols      = (const int*)d_in[5];
    const float* vals      = (const float*)d_in[6];
    const float* full_rows = (const float*)d_in[7];
    const int*   fri       = (const int*)d_in[8];
    float* out = (float*)d_out;

    __bf16* Wt = (__bf16*)d_ws;                                        // 32 MB: W^T (OUT_F, IN_F)
    __bf16* xb = (__bf16*)((char*)d_ws + (size_t)OUT_F * IN_F * 2);    // 64 MB: x bf16 (8192, 4096)

    k_dequant<<<dim3((IN_F / 8) * OUT_F / 256), 256, 0, stream>>>(qweight, lut, Wt);
    k_csr<<<dim3(OUT_F / 256), 256, 0, stream>>>(rows, cols, vals, Wt);
    k_topx<<<dim3(IN_F / 256), 256, 0, stream>>>(full_rows, fri, Wt);
    k_cvt<<<dim3((size_t)MTOK * IN_F / 8 / 256), 256, 0, stream>>>(x, xb);
    k_gemm<<<dim3(OUT_F / 128, MTOK / 128), 256, 0, stream>>>(xb, Wt, bias, out);
}

// Round 2
// 674.836 us; speedup vs baseline: 1.0823x; 1.0823x over previous
//
#include <hip/hip_runtime.h>
#include <hip/hip_bf16.h>
#include <stdint.h>

#define IN_F 4096
#define OUT_F 4096
#define MTOK 8192
#define TOPX_N 10

typedef __bf16 bf16x8 __attribute__((ext_vector_type(8)));
typedef float f32x4 __attribute__((ext_vector_type(4)));

__device__ __forceinline__ void gld_lds16(const void* g, void* l) {
    __builtin_amdgcn_global_load_lds((const __attribute__((address_space(1))) void*)g,
                                     (__attribute__((address_space(3))) void*)l, 16, 0, 0);
}

// ---------------------------------------------------------------------------
// 1) Dequant: W^T[j][k] = lut[j][code(k,j)], bf16, layout (OUT_F, IN_F).
//    LDS-staged transpose: block = 64 cols x 64 words.
//    - qweight staged coalesced (lanes along j), read back transposed via
//      pad-65 stride (lane*65+c -> bank (lane+c)%32, conflict-free).
//    - LUT staged to LDS; within a wave all lanes share one column -> the
//      8 gathers/word hit <=16 distinct addrs on 16 distinct banks (free).
//    - stores: lane = word index -> 64 consecutive bf16x8 = 1KB coalesced.
// ---------------------------------------------------------------------------
__global__ __launch_bounds__(256) void k_dequant(const int* __restrict__ qw,
                                                 const float* __restrict__ lut,
                                                 __bf16* __restrict__ Wt) {
    __shared__ int qs[64 * 65];
    __shared__ float ls[64 * 16];
    const int b = blockIdx.x;
    const int jc = (b & 63) * 64;   // column chunk base (64 chunks)
    const int wc = (b >> 6) * 64;   // word chunk base   (8 chunks of IN_F/8=512)
    const int t = threadIdx.x;

    // stage LUT: 64 cols x 16 floats, 4 threads per column
    {
        float4 v = *(const float4*)(lut + (size_t)(jc + (t >> 2)) * 16 + (t & 3) * 4);
        *(float4*)(ls + (t >> 2) * 16 + (t & 3) * 4) = v;
    }
    // stage qweight tile: 64 words x 64 cols, 4 x int4 per thread, coalesced
#pragma unroll
    for (int p = 0; p < 4; ++p) {
        int idx = t + p * 256;        // int4 index 0..1023
        int row = idx >> 4;           // word-local 0..63
        int c4 = (idx & 15) * 4;      // col-local
        int4 v = *(const int4*)(qw + (size_t)(wc + row) * OUT_F + jc + c4);
        int base = row * 65 + c4;
        qs[base] = v.x; qs[base + 1] = v.y; qs[base + 2] = v.z; qs[base + 3] = v.w;
    }
    __syncthreads();

    const int wave = t >> 6, lane = t & 63;
#pragma unroll
    for (int i = 0; i < 16; ++i) {
        const int c = wave * 16 + i;              // column-local (wave-uniform)
        const unsigned q = (unsigned)qs[lane * 65 + c];
        const float* lp = ls + c * 16;
        bf16x8 v;
#pragma unroll
        for (int e = 0; e < 8; ++e) v[e] = (__bf16)lp[(q >> (4 * e)) & 15];
        *(bf16x8*)(Wt + (size_t)(jc + c) * IN_F + (size_t)(wc + lane) * 8) = v;
    }
}

// ---------------------------------------------------------------------------
// 2) CSR outliers: row r owns interval [rows[r], rows[r+1]); no atomics.
//    64-thread blocks so 64 CUs carry the latency chains.
// ---------------------------------------------------------------------------
__global__ void k_csr(const int* __restrict__ rows, const int* __restrict__ cols,
                      const float* __restrict__ vals, __bf16* __restrict__ Wt) {
    int r = blockIdx.x * 64 + threadIdx.x;
    if (r >= OUT_F) return;
    int s = rows[r], e = rows[r + 1];
    __bf16* wrp = Wt + (size_t)r * IN_F;
    for (int n = s; n < e; ++n) {
        int c = cols[n];
        wrp[c] = (__bf16)((float)wrp[c] + vals[n]);
    }
}

// ---------------------------------------------------------------------------
// 3) topX dense outlier columns: W^T[fri[t]][i] += full_rows[i][t]
// ---------------------------------------------------------------------------
__global__ void k_topx(const float* __restrict__ fr, const int* __restrict__ fri,
                       __bf16* __restrict__ Wt) {
    int i = blockIdx.x * 256 + threadIdx.x;
    if (i >= IN_F) return;
#pragma unroll
    for (int t = 0; t < TOPX_N; ++t) {
        int j = fri[t];
        __bf16* p = Wt + (size_t)j * IN_F + i;
        *p = (__bf16)((float)*p + fr[(size_t)i * TOPX_N + t]);
    }
}

// ---------------------------------------------------------------------------
// 4) x fp32 -> bf16 (8 elements/thread)
// ---------------------------------------------------------------------------
__global__ void k_cvt(const float* __restrict__ x, __bf16* __restrict__ xb) {
    size_t t = (size_t)blockIdx.x * 256 + threadIdx.x;
    const float4* p = (const float4*)x + 2 * t;
    float4 a = p[0], b = p[1];
    bf16x8 v;
    v[0] = (__bf16)a.x; v[1] = (__bf16)a.y; v[2] = (__bf16)a.z; v[3] = (__bf16)a.w;
    v[4] = (__bf16)b.x; v[5] = (__bf16)b.y; v[6] = (__bf16)b.z; v[7] = (__bf16)b.w;
    ((bf16x8*)xb)[t] = v;
}

// ---------------------------------------------------------------------------
// 5) GEMM: C(8192x4096) = A(8192x4096,bf16) * B^T(4096x4096,bf16) + bias
//    m97 structure: 128x128 tile, BK=32, 4 waves x (4x4) 16x16x32 MFMAs,
//    global_load_lds width=16 staging, 2-barrier K-loop.
// ---------------------------------------------------------------------------
__global__ __launch_bounds__(256) void k_gemm(const __bf16* __restrict__ A,
                                              const __bf16* __restrict__ Bt,
                                              const float* __restrict__ bias,
                                              float* __restrict__ C) {
    __shared__ __align__(16) __bf16 As[128 * 32];
    __shared__ __align__(16) __bf16 Bs[128 * 32];
    const int tid = threadIdx.x;
    const int wave = tid >> 6;
    const int lane = tid & 63;
    const int m0 = blockIdx.y * 128;
    const int n0 = blockIdx.x * 128;
    const int wr = (wave >> 1) * 64;   // wave row offset within 128 tile
    const int wc = (wave & 1) * 64;    // wave col offset
    const int lrow = lane & 15;
    const int lk = lane >> 4;          // quad 0..3

    // staging: LDS byte o -> tile row o>>6, k-byte o&63 (rows are 64B = 32 bf16)
    const int o0 = wave * 2048 + lane * 16;
    const int o1 = o0 + 1024;
    const int r0 = o0 >> 6, kb0 = o0 & 63;
    const int r1 = o1 >> 6, kb1 = o1 & 63;

    const char* gA0 = (const char*)(A + (size_t)(m0 + r0) * IN_F) + kb0;
    const char* gA1 = (const char*)(A + (size_t)(m0 + r1) * IN_F) + kb1;
    const char* gB0 = (const char*)(Bt + (size_t)(n0 + r0) * IN_F) + kb0;
    const char* gB1 = (const char*)(Bt + (size_t)(n0 + r1) * IN_F) + kb1;
    char* lA0 = (char*)As + o0;
    char* lA1 = (char*)As + o1;
    char* lB0 = (char*)Bs + o0;
    char* lB1 = (char*)Bs + o1;

    f32x4 acc[4][4] = {};

    for (int k0 = 0; k0 < IN_F; k0 += 32) {
        gld_lds16(gA0, lA0);
        gld_lds16(gA1, lA1);
        gld_lds16(gB0, lB0);
        gld_lds16(gB1, lB1);
        gA0 += 64; gA1 += 64; gB0 += 64; gB1 += 64;
        __syncthreads();   // compiler drains vmcnt(0) before s_barrier

        bf16x8 af[4], bf[4];
#pragma unroll
        for (int i = 0; i < 4; ++i)
            af[i] = *(const bf16x8*)(As + (wr + i * 16 + lrow) * 32 + lk * 8);
#pragma unroll
        for (int j = 0; j < 4; ++j)
            bf[j] = *(const bf16x8*)(Bs + (wc + j * 16 + lrow) * 32 + lk * 8);

#pragma unroll
        for (int i = 0; i < 4; ++i)
#pragma unroll
            for (int j = 0; j < 4; ++j)
                acc[i][j] = __builtin_amdgcn_mfma_f32_16x16x32_bf16(af[i], bf[j], acc[i][j], 0, 0, 0);

        __syncthreads();   // protect LDS before next stage overwrites
    }

    // epilogue: C/D layout col=lane&15, row=(lane>>4)*4+reg  (m89/m91-verified)
#pragma unroll
    for (int j = 0; j < 4; ++j) {
        const int col = n0 + wc + j * 16 + lrow;
        const float bj = bias[col];
#pragma unroll
        for (int i = 0; i < 4; ++i) {
            const int mrow = m0 + wr + i * 16 + lk * 4;
#pragma unroll
            for (int r = 0; r < 4; ++r) {
                C[(size_t)(mrow + r) * OUT_F + col] = acc[i][j][r] + bj;
            }
        }
    }
}

extern "C" void kernel_launch(void* const* d_in, const int* in_sizes, int n_in,
                              void* d_out, int out_size, void* d_ws, size_t ws_size,
                              hipStream_t stream) {
    const float* x         = (const float*)d_in[0];
    const int*   qweight   = (const int*)d_in[1];
    const float* lut       = (const float*)d_in[2];
    const float* bias      = (const float*)d_in[3];
    const int*   rows      = (const int*)d_in[4];
    const int*   cols      = (const int*)d_in[5];
    const float* vals      = (const float*)d_in[6];
    const float* full_rows = (const float*)d_in[7];
    const int*   fri       = (const int*)d_in[8];
    float* out = (float*)d_out;

    __bf16* Wt = (__bf16*)d_ws;                                        // 32 MB: W^T (OUT_F, IN_F)
    __bf16* xb = (__bf16*)((char*)d_ws + (size_t)OUT_F * IN_F * 2);    // 64 MB: x bf16 (8192, 4096)

    k_dequant<<<dim3(64 * 8), 256, 0, stream>>>(qweight, lut, Wt);     // 64 col-chunks x 8 word-chunks
    k_csr<<<dim3(OUT_F / 64), 64, 0, stream>>>(rows, cols, vals, Wt);
    k_topx<<<dim3(IN_F / 256), 256, 0, stream>>>(full_rows, fri, Wt);
    k_cvt<<<dim3((size_t)MTOK * IN_F / 8 / 256), 256, 0, stream>>>(x, xb);
    k_gemm<<<dim3(OUT_F / 128, MTOK / 128), 256, 0, stream>>>(xb, Wt, bias, out);
}

// Round 3
// 557.336 us; speedup vs baseline: 1.3104x; 1.2108x over previous
//
#include <hip/hip_runtime.h>
#include <hip/hip_bf16.h>
#include <stdint.h>

#define IN_F 4096
#define OUT_F 4096
#define MTOK 8192
#define TOPX_N 10
#define NUMVALS 200000

typedef __bf16 bf16x8 __attribute__((ext_vector_type(8)));
typedef float f32x4 __attribute__((ext_vector_type(4)));

__device__ __forceinline__ void gld_lds16(const void* g, void* l) {
    __builtin_amdgcn_global_load_lds((const __attribute__((address_space(1))) void*)g,
                                     (__attribute__((address_space(3))) void*)l, 16, 0, 0);
}

// ---------------------------------------------------------------------------
// 1) Dequant: W^T[j][k] = lut[j][code(k,j)], bf16, layout (OUT_F, IN_F).
//    LDS-staged transpose: block = 64 cols x 64 words. (R1-verified, ~12 us)
// ---------------------------------------------------------------------------
__global__ __launch_bounds__(256) void k_dequant(const int* __restrict__ qw,
                                                 const float* __restrict__ lut,
                                                 __bf16* __restrict__ Wt) {
    __shared__ int qs[64 * 65];
    __shared__ float ls[64 * 16];
    const int b = blockIdx.x;
    const int jc = (b & 63) * 64;   // column chunk base (64 chunks)
    const int wc = (b >> 6) * 64;   // word chunk base   (8 chunks of IN_F/8=512)
    const int t = threadIdx.x;

    {
        float4 v = *(const float4*)(lut + (size_t)(jc + (t >> 2)) * 16 + (t & 3) * 4);
        *(float4*)(ls + (t >> 2) * 16 + (t & 3) * 4) = v;
    }
#pragma unroll
    for (int p = 0; p < 4; ++p) {
        int idx = t + p * 256;
        int row = idx >> 4;
        int c4 = (idx & 15) * 4;
        int4 v = *(const int4*)(qw + (size_t)(wc + row) * OUT_F + jc + c4);
        int base = row * 65 + c4;
        qs[base] = v.x; qs[base + 1] = v.y; qs[base + 2] = v.z; qs[base + 3] = v.w;
    }
    __syncthreads();

    const int wave = t >> 6, lane = t & 63;
#pragma unroll
    for (int i = 0; i < 16; ++i) {
        const int c = wave * 16 + i;
        const unsigned q = (unsigned)qs[lane * 65 + c];
        const float* lp = ls + c * 16;
        bf16x8 v;
#pragma unroll
        for (int e = 0; e < 8; ++e) v[e] = (__bf16)lp[(q >> (4 * e)) & 15];
        *(bf16x8*)(Wt + (size_t)(jc + c) * IN_F + (size_t)(wc + lane) * 8) = v;
    }
}

// ---------------------------------------------------------------------------
// 2) CSR outliers, nnz-parallel. r = upper_bound(rows, n) - 1 reproduces
//    searchsorted(side='right')-1 incl. empty rows. Duplicate (r,c) pairs and
//    adjacent-bf16 word sharing handled exactly via word-level CAS retry.
//    (Replaces row-parallel version whose max-gap straggler thread (~400
//     serial alias-stalled RMWs) cost ~270 us.)
// ---------------------------------------------------------------------------
__global__ __launch_bounds__(256) void k_csr(const int* __restrict__ rows,
                                             const int* __restrict__ cols,
                                             const float* __restrict__ vals,
                                             __bf16* __restrict__ Wt) {
    int n = blockIdx.x * 256 + threadIdx.x;
    if (n >= NUMVALS) return;
    // first idx in [0, OUT_F] with rows[idx] > n; r = idx - 1
    int lo = 0, hi = OUT_F + 1;
    while (lo < hi) {
        int mid = (lo + hi) >> 1;
        if (rows[mid] <= n) lo = mid + 1; else hi = mid;
    }
    int r = lo - 1;
    int c = cols[n];
    float v = vals[n];
    unsigned* wp = (unsigned*)Wt + (((size_t)r * IN_F + c) >> 1);
    unsigned sh = (c & 1) * 16;
    unsigned old = *wp, assumed;
    do {
        assumed = old;
        union { unsigned u; float f; } cv;
        cv.u = ((assumed >> sh) & 0xFFFFu) << 16;      // bf16 -> f32 (exact)
        __bf16 nb = (__bf16)(cv.f + v);
        unsigned nh = *(unsigned short*)&nb;
        unsigned newv = (assumed & ~(0xFFFFu << sh)) | (nh << sh);
        old = atomicCAS(wp, assumed, newv);
    } while (old != assumed);
}

// ---------------------------------------------------------------------------
// 3) topX dense outlier columns: W^T[fri[t]][i] += full_rows[i][t]
// ---------------------------------------------------------------------------
__global__ void k_topx(const float* __restrict__ fr, const int* __restrict__ fri,
                       __bf16* __restrict__ Wt) {
    int i = blockIdx.x * 256 + threadIdx.x;
    if (i >= IN_F) return;
#pragma unroll
    for (int t = 0; t < TOPX_N; ++t) {
        int j = fri[t];
        __bf16* p = Wt + (size_t)j * IN_F + i;
        *p = (__bf16)((float)*p + fr[(size_t)i * TOPX_N + t]);
    }
}

// ---------------------------------------------------------------------------
// 4) x fp32 -> bf16 (8 elements/thread)
// ---------------------------------------------------------------------------
__global__ void k_cvt(const float* __restrict__ x, __bf16* __restrict__ xb) {
    size_t t = (size_t)blockIdx.x * 256 + threadIdx.x;
    const float4* p = (const float4*)x + 2 * t;
    float4 a = p[0], b = p[1];
    bf16x8 v;
    v[0] = (__bf16)a.x; v[1] = (__bf16)a.y; v[2] = (__bf16)a.z; v[3] = (__bf16)a.w;
    v[4] = (__bf16)b.x; v[5] = (__bf16)b.y; v[6] = (__bf16)b.z; v[7] = (__bf16)b.w;
    ((bf16x8*)xb)[t] = v;
}

// ---------------------------------------------------------------------------
// 5) GEMM: C(8192x4096) = A(8192x4096,bf16) * B^T(4096x4096,bf16) + bias
//    m97 structure: 128x128 tile, BK=32, 4 waves x (4x4) 16x16x32 MFMAs,
//    global_load_lds width=16 staging, 2-barrier K-loop. (348 us, 797 TF)
// ---------------------------------------------------------------------------
__global__ __launch_bounds__(256) void k_gemm(const __bf16* __restrict__ A,
                                              const __bf16* __restrict__ Bt,
                                              const float* __restrict__ bias,
                                              float* __restrict__ C) {
    __shared__ __align__(16) __bf16 As[128 * 32];
    __shared__ __align__(16) __bf16 Bs[128 * 32];
    const int tid = threadIdx.x;
    const int wave = tid >> 6;
    const int lane = tid & 63;
    const int m0 = blockIdx.y * 128;
    const int n0 = blockIdx.x * 128;
    const int wr = (wave >> 1) * 64;
    const int wc = (wave & 1) * 64;
    const int lrow = lane & 15;
    const int lk = lane >> 4;

    const int o0 = wave * 2048 + lane * 16;
    const int o1 = o0 + 1024;
    const int r0 = o0 >> 6, kb0 = o0 & 63;
    const int r1 = o1 >> 6, kb1 = o1 & 63;

    const char* gA0 = (const char*)(A + (size_t)(m0 + r0) * IN_F) + kb0;
    const char* gA1 = (const char*)(A + (size_t)(m0 + r1) * IN_F) + kb1;
    const char* gB0 = (const char*)(Bt + (size_t)(n0 + r0) * IN_F) + kb0;
    const char* gB1 = (const char*)(Bt + (size_t)(n0 + r1) * IN_F) + kb1;
    char* lA0 = (char*)As + o0;
    char* lA1 = (char*)As + o1;
    char* lB0 = (char*)Bs + o0;
    char* lB1 = (char*)Bs + o1;

    f32x4 acc[4][4] = {};

    for (int k0 = 0; k0 < IN_F; k0 += 32) {
        gld_lds16(gA0, lA0);
        gld_lds16(gA1, lA1);
        gld_lds16(gB0, lB0);
        gld_lds16(gB1, lB1);
        gA0 += 64; gA1 += 64; gB0 += 64; gB1 += 64;
        __syncthreads();

        bf16x8 af[4], bf[4];
#pragma unroll
        for (int i = 0; i < 4; ++i)
            af[i] = *(const bf16x8*)(As + (wr + i * 16 + lrow) * 32 + lk * 8);
#pragma unroll
        for (int j = 0; j < 4; ++j)
            bf[j] = *(const bf16x8*)(Bs + (wc + j * 16 + lrow) * 32 + lk * 8);

#pragma unroll
        for (int i = 0; i < 4; ++i)
#pragma unroll
            for (int j = 0; j < 4; ++j)
                acc[i][j] = __builtin_amdgcn_mfma_f32_16x16x32_bf16(af[i], bf[j], acc[i][j], 0, 0, 0);

        __syncthreads();
    }

#pragma unroll
    for (int j = 0; j < 4; ++j) {
        const int col = n0 + wc + j * 16 + lrow;
        const float bj = bias[col];
#pragma unroll
        for (int i = 0; i < 4; ++i) {
            const int mrow = m0 + wr + i * 16 + lk * 4;
#pragma unroll
            for (int r = 0; r < 4; ++r) {
                C[(size_t)(mrow + r) * OUT_F + col] = acc[i][j][r] + bj;
            }
        }
    }
}

extern "C" void kernel_launch(void* const* d_in, const int* in_sizes, int n_in,
                              void* d_out, int out_size, void* d_ws, size_t ws_size,
                              hipStream_t stream) {
    const float* x         = (const float*)d_in[0];
    const int*   qweight   = (const int*)d_in[1];
    const float* lut       = (const float*)d_in[2];
    const float* bias      = (const float*)d_in[3];
    const int*   rows      = (const int*)d_in[4];
    const int*   cols      = (const int*)d_in[5];
    const float* vals      = (const float*)d_in[6];
    const float* full_rows = (const float*)d_in[7];
    const int*   fri       = (const int*)d_in[8];
    float* out = (float*)d_out;

    __bf16* Wt = (__bf16*)d_ws;                                        // 32 MB: W^T (OUT_F, IN_F)
    __bf16* xb = (__bf16*)((char*)d_ws + (size_t)OUT_F * IN_F * 2);    // 64 MB: x bf16 (8192, 4096)

    k_dequant<<<dim3(64 * 8), 256, 0, stream>>>(qweight, lut, Wt);
    k_csr<<<dim3((NUMVALS + 255) / 256), 256, 0, stream>>>(rows, cols, vals, Wt);
    k_topx<<<dim3(IN_F / 256), 256, 0, stream>>>(full_rows, fri, Wt);
    k_cvt<<<dim3((size_t)MTOK * IN_F / 8 / 256), 256, 0, stream>>>(x, xb);
    k_gemm<<<dim3(OUT_F / 128, MTOK / 128), 256, 0, stream>>>(xb, Wt, bias, out);
}